// Round 13
// baseline (564.789 us; speedup 1.0000x reference)
//
#include <hip/hip_runtime.h>

#define Vn 128
#define En 32
#define Hn 128
#define Bn 4
#define Sn 512
#define G4H 512   // 4*Hn

typedef _Float16 half8 __attribute__((ext_vector_type(8)));
typedef float    floatx4 __attribute__((ext_vector_type(4)));

__device__ __forceinline__ float fsigmoid(float x) {
    return 1.0f / (1.0f + __expf(-x));
}

// tanh without abs/copysign: 1 - 2/(e^{2x}+1); saturates correctly, no NaN.
__device__ __forceinline__ float ftanh(float x) {
    float e = __expf(2.0f * x);
    return 1.0f - 2.0f / (e + 1.0f);
}

// ---------------------------------------------------------------------------
// Kernel A': Gtab, GATE-INTERLEAVED: Gtab[v][j][g] (g fastest).
// ---------------------------------------------------------------------------
__global__ __launch_bounds__(512) void k_gtab(
        const float* __restrict__ emb, const float* __restrict__ Wih,
        const float* __restrict__ bih, const float* __restrict__ bhh,
        float* __restrict__ Gtab) {
    int v = blockIdx.x;
    int g = threadIdx.x;            // g = gate*128 + j
    __shared__ float e[En];
    if (g < En) e[g] = emb[v * En + g];
    __syncthreads();
    const float4* wr = (const float4*)(Wih + g * En);
    float acc = bih[g] + bhh[g];
#pragma unroll
    for (int i = 0; i < En / 4; i++) {
        float4 w4 = wr[i];
        acc += w4.x * e[4*i] + w4.y * e[4*i+1] + w4.z * e[4*i+2] + w4.w * e[4*i+3];
    }
    Gtab[v * G4H + (g & 127) * 4 + (g >> 7)] = acc;   // [v][j][gate]
}

// ---------------------------------------------------------------------------
// Kernel B (R17 = R16 + 2-way independent MFMA accumulators):
// R16 lesson: VALU-issue is NOT the critical path (deleting instrs changed
// nothing) -> the serial latency chain is. This round shortens the MFMA
// segment: each gate's 4-deep dependent chain -> two independent 2-chains
// + one float4 add (latency ~halved; +16 VALU, proven free).
// ---------------------------------------------------------------------------
__global__ __attribute__((amdgpu_flat_work_group_size(512, 512),
                          amdgpu_waves_per_eu(2, 2)))
void k_lstm(
        const float* __restrict__ Whh, const float* __restrict__ Gtab,
        const int* __restrict__ x,
        float* __restrict__ out, float* __restrict__ hT, float* __restrict__ cT) {
    int tid = threadIdx.x;
    int wv  = tid >> 6;    // wave 0..7: owns j-range [16wv, 16wv+16)
    int l   = tid & 63;
    int cn  = l & 15;      // MFMA A-row within tile
    int kg  = l >> 4;      // k-group 0..3
    int cb  = l & 3;       // batch for B-frag load (col c = batch c&3)
    int jr  = l >> 2;      // activation: row within tile (0..15)
    int bb  = l & 3;       // activation: batch
    int aj  = 16 * wv + jr; // activation: global row j

    bool r1 = (l >> 2) & 1;   // loop-invariant select bits: r = (l>>2)&3
    bool r2 = (l >> 2) & 2;

    __shared__ int xb[4][520];                       // PRE-SCALED byte offsets
    __shared__ alignas(16) _Float16 hbuf[2][4][144]; // h fp16, double-buffered

    for (int i = tid; i < Bn * Sn; i += 512) xb[i >> 9][i & 511] = x[i] * 2048;
    if (tid < 4) xb[tid][512] = 0;                   // sentinel for s=511 prefetch
    for (int i = tid; i < 2 * 4 * 144; i += 512) ((_Float16*)hbuf)[i] = (_Float16)0.0f;

    // ---- A-fragments: af[gate][kc], loaded + converted ONCE ----
    half8 af[4][4];
#pragma unroll
    for (int g = 0; g < 4; g++) {
#pragma unroll
        for (int kc = 0; kc < 4; kc++) {
            int row = g * Hn + 16 * wv + cn;
            int kb  = kc * 32 + kg * 8;
            const float4* p = (const float4*)(Whh + row * Hn + kb);
            float4 lo = p[0], hi = p[1];
            half8 a = { (_Float16)lo.x, (_Float16)lo.y, (_Float16)lo.z, (_Float16)lo.w,
                        (_Float16)hi.x, (_Float16)hi.y, (_Float16)hi.z, (_Float16)hi.w };
            af[g][kc] = a;
        }
    }

    float c_ = 0.f, h_ = 0.f;
    const char* gbase = (const char*)Gtab + aj * 16;   // + xb byte offset
    float* outp = out + bb * Sn * Hn + aj;
    __syncthreads();

    float4 gx4 = *(const float4*)(gbase + xb[bb][0]);

#pragma unroll 2
    for (int s = 0; s < Sn; s++) {
        // B-fragments from hbuf[s&1]: col = batch, k = kc*32+kg*8+(0..7)
        half8 bf[4];
#pragma unroll
        for (int kc = 0; kc < 4; kc++)
            bf[kc] = *(const half8*)&hbuf[s & 1][cb][kc * 32 + kg * 8];

        // 16 MFMAs: 4 gates x (2 independent 2-chains) -> halved dep latency
        floatx4 d[4];
#pragma unroll
        for (int g = 0; g < 4; g++) {
            floatx4 a0 = { 0.f, 0.f, 0.f, 0.f };
            floatx4 a1 = { 0.f, 0.f, 0.f, 0.f };
            a0 = __builtin_amdgcn_mfma_f32_16x16x32_f16(af[g][0], bf[0], a0, 0, 0, 0);
            a1 = __builtin_amdgcn_mfma_f32_16x16x32_f16(af[g][2], bf[2], a1, 0, 0, 0);
            a0 = __builtin_amdgcn_mfma_f32_16x16x32_f16(af[g][1], bf[1], a0, 0, 0, 0);
            a1 = __builtin_amdgcn_mfma_f32_16x16x32_f16(af[g][3], bf[3], a1, 0, 0, 0);
            d[g] = a0 + a1;
        }

        // prefetch NEXT step's gx (sentinel makes s=511 safe)
        float4 ngx = *(const float4*)(gbase + xb[bb][s + 1]);

        // direct select: lane's own reg r = (l>>2)&3 IS (row jr, batch bb)
        float ex[4];
#pragma unroll
        for (int g = 0; g < 4; g++) {
            float lo = r1 ? d[g][1] : d[g][0];
            float hi = r1 ? d[g][3] : d[g][2];
            ex[g] = r2 ? hi : lo;
        }

        float gi = gx4.x + ex[0];
        float gf = gx4.y + ex[1];
        float gg = gx4.z + ex[2];
        float go = gx4.w + ex[3];
        c_ = fsigmoid(gf) * c_ + fsigmoid(gi) * ftanh(gg);
        h_ = fsigmoid(go) * ftanh(c_);

        *outp = h_;  outp += Hn;                 // fire-and-forget
        hbuf[(s & 1) ^ 1][bb][aj] = (_Float16)h_;

        gx4 = ngx;
        // LDS-only barrier: hbuf visible to all waves; vmcnt NOT drained.
        asm volatile("s_waitcnt lgkmcnt(0)\n\ts_barrier" ::: "memory");
    }
    hT[bb * Hn + aj] = h_;
    cT[bb * Hn + aj] = c_;
}

// ---------------------------------------------------------------------------
// Kernel C (R17): K-GEMV writing TRANSPOSED koT[b][u][i][4]:
// koT float4-chunk u of k_i lives at float4 index b*16384 + u*512 + i, so
// k_attn's score phase (lane = i) reads CONSECUTIVE 16B per lane = coalesced.
// The scattered write here happens once per element (cheap); the read
// happened once per (t,i) pair (the R16 k_attn gather was ~64 cacheline
// transactions per wave instruction -- the hidden 150us).
// ---------------------------------------------------------------------------
__global__ __launch_bounds__(128) void k_k(
        const float* __restrict__ out, const float* __restrict__ Wk,
        const float* __restrict__ bk, float* __restrict__ koT) {
    int bs  = blockIdx.x;
    int b   = bs >> 9;
    int s   = bs & (Sn - 1);
    int tid = threadIdx.x;
    __shared__ float o[Hn];
    o[tid] = out[bs * Hn + tid];
    __syncthreads();
    const float4* wr = (const float4*)(Wk + tid * Hn);
    float acc = bk[tid];
#pragma unroll
    for (int i = 0; i < Hn / 4; i++) {
        float4 w4 = wr[i];
        acc += w4.x * o[4*i] + w4.y * o[4*i+1] + w4.z * o[4*i+2] + w4.w * o[4*i+3];
    }
    koT[b * 65536 + (tid >> 2) * 2048 + s * 4 + (tid & 3)] = acc;
}

// ---------------------------------------------------------------------------
// Kernel D (R17): FUSED q-GEMV + scores (coalesced koT reads) + softmax +
// ctx + logits GEMV. Block per (b,t), 512 threads.
// ---------------------------------------------------------------------------
__global__ __launch_bounds__(512) void k_attn(
        const float* __restrict__ koT, const float* __restrict__ vvec,
        const float* __restrict__ out,
        const float* __restrict__ Wq, const float* __restrict__ bq,
        const float* __restrict__ Wf, const float* __restrict__ bf,
        float* __restrict__ logits) {
    int b   = blockIdx.x >> 9;
    int t   = blockIdx.x & (Sn - 1);
    int tid = threadIdx.x;
    int wv  = tid >> 6;
    __shared__ float qs[Hn];
    __shared__ float vs[Hn];
    __shared__ float oc[2 * Hn];   // [out_t | ctx_t]
    __shared__ float sc[Sn];
    __shared__ float wmax[8];
    __shared__ float wsum[8];
    __shared__ float part[16][Hn];

    if (tid < Hn) {
        oc[tid] = out[(b * Sn + t) * Hn + tid];
        vs[tid] = vvec[tid];
    }
    __syncthreads();

    // --- q_t = bq + Wq @ out_t: thread (h = tid&127, kq = tid>>7) ---
    {
        int h = tid & 127, kq = tid >> 7;
        const float4* wr = (const float4*)(Wq + h * Hn + kq * 32);
        const float* ob = oc + kq * 32;
        float a = 0.0f;
#pragma unroll
        for (int i = 0; i < 8; i++) {
            float4 w4 = wr[i];
            a += w4.x * ob[4*i] + w4.y * ob[4*i+1] + w4.z * ob[4*i+2] + w4.w * ob[4*i+3];
        }
        part[kq][h] = a;
    }
    __syncthreads();
    if (tid < Hn)
        qs[tid] = bq[tid] + part[0][tid] + part[1][tid] + part[2][tid] + part[3][tid];
    __syncthreads();

    // --- scores: thread tid = key index i; koT reads are COALESCED ---
    float a = -1e30f;
    if (tid <= t) {
        const float4* kT = (const float4*)koT + b * 16384 + tid;
        float s = 0.0f;
#pragma unroll
        for (int u = 0; u < Hn / 4; u++) {
            float4 k4 = kT[u * 512];
            s += vs[4*u]   * ftanh(qs[4*u]   + k4.x);
            s += vs[4*u+1] * ftanh(qs[4*u+1] + k4.y);
            s += vs[4*u+2] * ftanh(qs[4*u+2] + k4.z);
            s += vs[4*u+3] * ftanh(qs[4*u+3] + k4.w);
        }
        sc[tid] = s;
        a = s;
    }
#pragma unroll
    for (int off = 32; off > 0; off >>= 1) a = fmaxf(a, __shfl_xor(a, off));
    if ((tid & 63) == 0) wmax[wv] = a;
    __syncthreads();
    float m = wmax[0];
#pragma unroll
    for (int r = 1; r < 8; r++) m = fmaxf(m, wmax[r]);

    float ev = 0.0f;
    if (tid <= t) {
        ev = __expf(sc[tid] - m);
        sc[tid] = ev;
    }
    float ssum = ev;
#pragma unroll
    for (int off = 32; off > 0; off >>= 1) ssum += __shfl_xor(ssum, off);
    if ((tid & 63) == 0) wsum[wv] = ssum;
    __syncthreads();
    float tot = wsum[0];
#pragma unroll
    for (int r = 1; r < 8; r++) tot += wsum[r];
    float inv = 1.0f / tot;

    // --- ctx: i-slice = tid>>5 (16 slices), float4 column = tid&31 ---
    int hq = tid & 31;
    int is = tid >> 5;
    float4 acc = {0.0f, 0.0f, 0.0f, 0.0f};
    const float4* ob4 = (const float4*)(out + b * Sn * Hn);
    for (int i = is; i <= t; i += 16) {
        float s = sc[i];
        float4 o4 = ob4[i * (Hn / 4) + hq];
        acc.x += s * o4.x; acc.y += s * o4.y;
        acc.z += s * o4.z; acc.w += s * o4.w;
    }
    ((float4*)part[is])[hq] = acc;
    __syncthreads();
    if (tid < Hn) {
        float sum2 = 0.0f;
#pragma unroll
        for (int r = 0; r < 16; r++) sum2 += part[r][tid];
        oc[Hn + tid] = sum2 * inv;     // ctx stays in LDS
    }
    __syncthreads();

    // --- logits = bf + Wf @ [out_t | ctx_t]: thread (v = tid&127, kq) ---
    {
        int v = tid & 127, kq = tid >> 7;
        const float4* wr = (const float4*)(Wf + v * 2 * Hn + kq * 64);
        const float* ob = oc + kq * 64;
        float a2 = 0.0f;
#pragma unroll
        for (int i = 0; i < 16; i++) {
            float4 w4 = wr[i];
            a2 += w4.x * ob[4*i] + w4.y * ob[4*i+1] + w4.z * ob[4*i+2] + w4.w * ob[4*i+3];
        }
        part[kq][v] = a2;
    }
    __syncthreads();
    if (tid < Hn)
        logits[(b * Sn + t) * Vn + tid] =
            bf[tid] + part[0][tid] + part[1][tid] + part[2][tid] + part[3][tid];
}

extern "C" void kernel_launch(void* const* d_in, const int* in_sizes, int n_in,
                              void* d_out, int out_size, void* d_ws, size_t ws_size,
                              hipStream_t stream) {
    const int*   x   = (const int*)d_in[0];
    const float* emb = (const float*)d_in[1];
    const float* Wih = (const float*)d_in[2];
    const float* Whh = (const float*)d_in[3];
    const float* bih = (const float*)d_in[4];
    const float* bhh = (const float*)d_in[5];
    const float* Wq  = (const float*)d_in[6];
    const float* bq  = (const float*)d_in[7];
    const float* Wk  = (const float*)d_in[8];
    const float* bk  = (const float*)d_in[9];
    const float* v   = (const float*)d_in[10];
    const float* Wf  = (const float*)d_in[11];
    const float* bf  = (const float*)d_in[12];

    float* logits = (float*)d_out;                 // (B,S,V) = 262144
    float* hT     = logits + Bn * Sn * Vn;         // (B,H)   = 512
    float* cT     = hT + Bn * Hn;                  // (B,H)   = 512

    float* ws   = (float*)d_ws;
    float* Gtab = ws;                               // V*4H   = 65536 floats
    float* outb = ws + 65536;                       // B*S*H  = 262144
    float* koT  = ws + 65536 + 262144;              // B*S*H  = 262144 (transposed)

    k_gtab<<<Vn, 512, 0, stream>>>(emb, Wih, bih, bhh, Gtab);
    k_lstm<<<1, 512, 0, stream>>>(Whh, Gtab, x, outb, hT, cT);
    k_k<<<Bn * Sn, 128, 0, stream>>>(outb, Wk, bk, koT);
    k_attn<<<Bn * Sn, 512, 0, stream>>>(koT, v, outb, Wq, bq, Wf, bf, logits);
}

// Round 14
// 517.862 us; speedup vs baseline: 1.0906x; 1.0906x over previous
//
#include <hip/hip_runtime.h>

#define Vn 128
#define En 32
#define Hn 128
#define Bn 4
#define Sn 512
#define G4H 512   // 4*Hn

typedef _Float16 half8 __attribute__((ext_vector_type(8)));
typedef float    floatx4 __attribute__((ext_vector_type(4)));

__device__ __forceinline__ float fsigmoid(float x) {
    return 1.0f / (1.0f + __expf(-x));
}

// tanh without abs/copysign: 1 - 2/(e^{2x}+1); saturates correctly, no NaN.
__device__ __forceinline__ float ftanh(float x) {
    float e = __expf(2.0f * x);
    return 1.0f - 2.0f / (e + 1.0f);
}

// ---------------------------------------------------------------------------
// Kernel A': Gtab, GATE-INTERLEAVED: Gtab[v][j][g] (g fastest).
// ---------------------------------------------------------------------------
__global__ __launch_bounds__(512) void k_gtab(
        const float* __restrict__ emb, const float* __restrict__ Wih,
        const float* __restrict__ bih, const float* __restrict__ bhh,
        float* __restrict__ Gtab) {
    int v = blockIdx.x;
    int g = threadIdx.x;            // g = gate*128 + j
    __shared__ float e[En];
    if (g < En) e[g] = emb[v * En + g];
    __syncthreads();
    const float4* wr = (const float4*)(Wih + g * En);
    float acc = bih[g] + bhh[g];
#pragma unroll
    for (int i = 0; i < En / 4; i++) {
        float4 w4 = wr[i];
        acc += w4.x * e[4*i] + w4.y * e[4*i+1] + w4.z * e[4*i+2] + w4.w * e[4*i+3];
    }
    Gtab[v * G4H + (g & 127) * 4 + (g >> 7)] = acc;   // [v][j][gate]
}

// ---------------------------------------------------------------------------
// Kernel B (R18 = R16 exact, the proven 320us version): MFMA LSTM.
//
// R17 post-mortem pinned the regime: per-SIMD ISSUE-bound (2 waves x ~410
// issue-cyc). The 2-way accumulator split added ~48 real instrs/wave
// (inits + accvgpr_reads + adds) = +218 cyc/step -> reverted to the 4-deep
// chain. R16's deletions were phantom (already compiler-eliminated), hence
// neutral. The remaining fat is the structural 4x batch-column redundancy,
// which no 16x16 operand arrangement avoids at B=4.
// ---------------------------------------------------------------------------
__global__ __attribute__((amdgpu_flat_work_group_size(512, 512),
                          amdgpu_waves_per_eu(2, 2)))
void k_lstm(
        const float* __restrict__ Whh, const float* __restrict__ Gtab,
        const int* __restrict__ x,
        float* __restrict__ out, float* __restrict__ hT, float* __restrict__ cT) {
    int tid = threadIdx.x;
    int wv  = tid >> 6;    // wave 0..7: owns j-range [16wv, 16wv+16)
    int l   = tid & 63;
    int cn  = l & 15;      // MFMA A-row within tile
    int kg  = l >> 4;      // k-group 0..3
    int cb  = l & 3;       // batch for B-frag load (col c = batch c&3)
    int jr  = l >> 2;      // activation: row within tile (0..15)
    int bb  = l & 3;       // activation: batch
    int aj  = 16 * wv + jr; // activation: global row j

    bool r1 = (l >> 2) & 1;   // loop-invariant select bits: r = (l>>2)&3
    bool r2 = (l >> 2) & 2;

    __shared__ int xb[4][520];                       // PRE-SCALED byte offsets
    __shared__ alignas(16) _Float16 hbuf[2][4][144]; // h fp16, double-buffered

    for (int i = tid; i < Bn * Sn; i += 512) xb[i >> 9][i & 511] = x[i] * 2048;
    if (tid < 4) xb[tid][512] = 0;                   // sentinel for s=511 prefetch
    for (int i = tid; i < 2 * 4 * 144; i += 512) ((_Float16*)hbuf)[i] = (_Float16)0.0f;

    // ---- A-fragments: af[gate][kc], loaded + converted ONCE ----
    half8 af[4][4];
#pragma unroll
    for (int g = 0; g < 4; g++) {
#pragma unroll
        for (int kc = 0; kc < 4; kc++) {
            int row = g * Hn + 16 * wv + cn;
            int kb  = kc * 32 + kg * 8;
            const float4* p = (const float4*)(Whh + row * Hn + kb);
            float4 lo = p[0], hi = p[1];
            half8 a = { (_Float16)lo.x, (_Float16)lo.y, (_Float16)lo.z, (_Float16)lo.w,
                        (_Float16)hi.x, (_Float16)hi.y, (_Float16)hi.z, (_Float16)hi.w };
            af[g][kc] = a;
        }
    }

    float c_ = 0.f, h_ = 0.f;
    const char* gbase = (const char*)Gtab + aj * 16;   // + xb byte offset
    float* outp = out + bb * Sn * Hn + aj;
    __syncthreads();

    float4 gx4 = *(const float4*)(gbase + xb[bb][0]);

#pragma unroll 2
    for (int s = 0; s < Sn; s++) {
        // B-fragments from hbuf[s&1]: col = batch, k = kc*32+kg*8+(0..7)
        half8 bf[4];
#pragma unroll
        for (int kc = 0; kc < 4; kc++)
            bf[kc] = *(const half8*)&hbuf[s & 1][cb][kc * 32 + kg * 8];

        // 16 MFMAs: 4 gates x 4 K-chunks, fp32 accumulate
        floatx4 d[4];
#pragma unroll
        for (int g = 0; g < 4; g++) {
            floatx4 acc = { 0.f, 0.f, 0.f, 0.f };
#pragma unroll
            for (int kc = 0; kc < 4; kc++)
                acc = __builtin_amdgcn_mfma_f32_16x16x32_f16(af[g][kc], bf[kc], acc, 0, 0, 0);
            d[g] = acc;
        }

        // prefetch NEXT step's gx (sentinel makes s=511 safe)
        float4 ngx = *(const float4*)(gbase + xb[bb][s + 1]);

        // direct select: lane's own reg r = (l>>2)&3 IS (row jr, batch bb)
        float ex[4];
#pragma unroll
        for (int g = 0; g < 4; g++) {
            float lo = r1 ? d[g][1] : d[g][0];
            float hi = r1 ? d[g][3] : d[g][2];
            ex[g] = r2 ? hi : lo;
        }

        float gi = gx4.x + ex[0];
        float gf = gx4.y + ex[1];
        float gg = gx4.z + ex[2];
        float go = gx4.w + ex[3];
        c_ = fsigmoid(gf) * c_ + fsigmoid(gi) * ftanh(gg);
        h_ = fsigmoid(go) * ftanh(c_);

        *outp = h_;  outp += Hn;                 // fire-and-forget
        hbuf[(s & 1) ^ 1][bb][aj] = (_Float16)h_;

        gx4 = ngx;
        // LDS-only barrier: hbuf visible to all waves; vmcnt NOT drained.
        asm volatile("s_waitcnt lgkmcnt(0)\n\ts_barrier" ::: "memory");
    }
    hT[bb * Hn + aj] = h_;
    cT[bb * Hn + aj] = c_;
}

// ---------------------------------------------------------------------------
// Kernel C: K-GEMV writing TRANSPOSED koT[b][u][i][4] (kept from R17:
// neutral, and keeps k_attn's score reads coalesced).
// ---------------------------------------------------------------------------
__global__ __launch_bounds__(128) void k_k(
        const float* __restrict__ out, const float* __restrict__ Wk,
        const float* __restrict__ bk, float* __restrict__ koT) {
    int bs  = blockIdx.x;
    int b   = bs >> 9;
    int s   = bs & (Sn - 1);
    int tid = threadIdx.x;
    __shared__ float o[Hn];
    o[tid] = out[bs * Hn + tid];
    __syncthreads();
    const float4* wr = (const float4*)(Wk + tid * Hn);
    float acc = bk[tid];
#pragma unroll
    for (int i = 0; i < Hn / 4; i++) {
        float4 w4 = wr[i];
        acc += w4.x * o[4*i] + w4.y * o[4*i+1] + w4.z * o[4*i+2] + w4.w * o[4*i+3];
    }
    koT[b * 65536 + (tid >> 2) * 2048 + s * 4 + (tid & 3)] = acc;
}

// ---------------------------------------------------------------------------
// Kernel D: FUSED q-GEMV + scores + softmax + ctx + logits GEMV.
// Block per (b,t), 512 threads. ctx never leaves LDS.
// ---------------------------------------------------------------------------
__global__ __launch_bounds__(512) void k_attn(
        const float* __restrict__ koT, const float* __restrict__ vvec,
        const float* __restrict__ out,
        const float* __restrict__ Wq, const float* __restrict__ bq,
        const float* __restrict__ Wf, const float* __restrict__ bf,
        float* __restrict__ logits) {
    int b   = blockIdx.x >> 9;
    int t   = blockIdx.x & (Sn - 1);
    int tid = threadIdx.x;
    int wv  = tid >> 6;
    __shared__ float qs[Hn];
    __shared__ float vs[Hn];
    __shared__ float oc[2 * Hn];   // [out_t | ctx_t]
    __shared__ float sc[Sn];
    __shared__ float wmax[8];
    __shared__ float wsum[8];
    __shared__ float part[16][Hn];

    if (tid < Hn) {
        oc[tid] = out[(b * Sn + t) * Hn + tid];
        vs[tid] = vvec[tid];
    }
    __syncthreads();

    // --- q_t = bq + Wq @ out_t: thread (h = tid&127, kq = tid>>7) ---
    {
        int h = tid & 127, kq = tid >> 7;
        const float4* wr = (const float4*)(Wq + h * Hn + kq * 32);
        const float* ob = oc + kq * 32;
        float a = 0.0f;
#pragma unroll
        for (int i = 0; i < 8; i++) {
            float4 w4 = wr[i];
            a += w4.x * ob[4*i] + w4.y * ob[4*i+1] + w4.z * ob[4*i+2] + w4.w * ob[4*i+3];
        }
        part[kq][h] = a;
    }
    __syncthreads();
    if (tid < Hn)
        qs[tid] = bq[tid] + part[0][tid] + part[1][tid] + part[2][tid] + part[3][tid];
    __syncthreads();

    // --- scores: thread tid = key index i; koT reads coalesced ---
    float a = -1e30f;
    if (tid <= t) {
        const float4* kT = (const float4*)koT + b * 16384 + tid;
        float s = 0.0f;
#pragma unroll
        for (int u = 0; u < Hn / 4; u++) {
            float4 k4 = kT[u * 512];
            s += vs[4*u]   * ftanh(qs[4*u]   + k4.x);
            s += vs[4*u+1] * ftanh(qs[4*u+1] + k4.y);
            s += vs[4*u+2] * ftanh(qs[4*u+2] + k4.z);
            s += vs[4*u+3] * ftanh(qs[4*u+3] + k4.w);
        }
        sc[tid] = s;
        a = s;
    }
#pragma unroll
    for (int off = 32; off > 0; off >>= 1) a = fmaxf(a, __shfl_xor(a, off));
    if ((tid & 63) == 0) wmax[wv] = a;
    __syncthreads();
    float m = wmax[0];
#pragma unroll
    for (int r = 1; r < 8; r++) m = fmaxf(m, wmax[r]);

    float ev = 0.0f;
    if (tid <= t) {
        ev = __expf(sc[tid] - m);
        sc[tid] = ev;
    }
    float ssum = ev;
#pragma unroll
    for (int off = 32; off > 0; off >>= 1) ssum += __shfl_xor(ssum, off);
    if ((tid & 63) == 0) wsum[wv] = ssum;
    __syncthreads();
    float tot = wsum[0];
#pragma unroll
    for (int r = 1; r < 8; r++) tot += wsum[r];
    float inv = 1.0f / tot;

    // --- ctx: i-slice = tid>>5 (16 slices), float4 column = tid&31 ---
    int hq = tid & 31;
    int is = tid >> 5;
    float4 acc = {0.0f, 0.0f, 0.0f, 0.0f};
    const float4* ob4 = (const float4*)(out + b * Sn * Hn);
    for (int i = is; i <= t; i += 16) {
        float s = sc[i];
        float4 o4 = ob4[i * (Hn / 4) + hq];
        acc.x += s * o4.x; acc.y += s * o4.y;
        acc.z += s * o4.z; acc.w += s * o4.w;
    }
    ((float4*)part[is])[hq] = acc;
    __syncthreads();
    if (tid < Hn) {
        float sum2 = 0.0f;
#pragma unroll
        for (int r = 0; r < 16; r++) sum2 += part[r][tid];
        oc[Hn + tid] = sum2 * inv;     // ctx stays in LDS
    }
    __syncthreads();

    // --- logits = bf + Wf @ [out_t | ctx_t]: thread (v = tid&127, kq) ---
    {
        int v = tid & 127, kq = tid >> 7;
        const float4* wr = (const float4*)(Wf + v * 2 * Hn + kq * 64);
        const float* ob = oc + kq * 64;
        float a2 = 0.0f;
#pragma unroll
        for (int i = 0; i < 16; i++) {
            float4 w4 = wr[i];
            a2 += w4.x * ob[4*i] + w4.y * ob[4*i+1] + w4.z * ob[4*i+2] + w4.w * ob[4*i+3];
        }
        part[kq][v] = a2;
    }
    __syncthreads();
    if (tid < Hn)
        logits[(b * Sn + t) * Vn + tid] =
            bf[tid] + part[0][tid] + part[1][tid] + part[2][tid] + part[3][tid];
}

extern "C" void kernel_launch(void* const* d_in, const int* in_sizes, int n_in,
                              void* d_out, int out_size, void* d_ws, size_t ws_size,
                              hipStream_t stream) {
    const int*   x   = (const int*)d_in[0];
    const float* emb = (const float*)d_in[1];
    const float* Wih = (const float*)d_in[2];
    const float* Whh = (const float*)d_in[3];
    const float* bih = (const float*)d_in[4];
    const float* bhh = (const float*)d_in[5];
    const float* Wq  = (const float*)d_in[6];
    const float* bq  = (const float*)d_in[7];
    const float* Wk  = (const float*)d_in[8];
    const float* bk  = (const float*)d_in[9];
    const float* v   = (const float*)d_in[10];
    const float* Wf  = (const float*)d_in[11];
    const float* bf  = (const float*)d_in[12];

    float* logits = (float*)d_out;                 // (B,S,V) = 262144
    float* hT     = logits + Bn * Sn * Vn;         // (B,H)   = 512
    float* cT     = hT + Bn * Hn;                  // (B,H)   = 512

    float* ws   = (float*)d_ws;
    float* Gtab = ws;                               // V*4H   = 65536 floats
    float* outb = ws + 65536;                       // B*S*H  = 262144
    float* koT  = ws + 65536 + 262144;              // B*S*H  = 262144 (transposed)

    k_gtab<<<Vn, 512, 0, stream>>>(emb, Wih, bih, bhh, Gtab);
    k_lstm<<<1, 512, 0, stream>>>(Whh, Gtab, x, outb, hT, cT);
    k_k<<<Bn * Sn, 128, 0, stream>>>(outb, Wk, bk, koT);
    k_attn<<<Bn * Sn, 512, 0, stream>>>(koT, v, outb, Wq, bq, Wf, bf, logits);
}

// Round 15
// 442.371 us; speedup vs baseline: 1.2767x; 1.1706x over previous
//
#include <hip/hip_runtime.h>

#define Vn 128
#define En 32
#define Hn 128
#define Bn 4
#define Sn 512
#define G4H 512   // 4*Hn

typedef _Float16 half8 __attribute__((ext_vector_type(8)));
typedef float    floatx4 __attribute__((ext_vector_type(4)));

// Raw v_rcp_f32 (~1 ULP). Without -ffast-math, 1.0f/x is a ~12-instr IEEE
// divide sequence (div_scale + rcp + 3 fma Newton + div_fmas + div_fixup);
// at 6 divides/step in k_lstm that was ~1/3 of the whole step's issue.
__device__ __forceinline__ float frcp(float x) {
    return __builtin_amdgcn_rcpf(x);
}

__device__ __forceinline__ float fsigmoid(float x) {
    return frcp(1.0f + __expf(-x));   // e^-x=inf -> rcp(inf)=0: safe
}

// tanh = 1 - 2/(e^{2x}+1); e->0 gives -1, e->inf gives +1, never NaN.
__device__ __forceinline__ float ftanh(float x) {
    float e = __expf(2.0f * x);
    return 1.0f - 2.0f * frcp(e + 1.0f);
}

// ---------------------------------------------------------------------------
// Kernel B (R19): MFMA LSTM with FUSED Gtab prologue + rcp activations.
// Gtab[v][j][g] (gate-interleaved) is computed in a ~2us prologue (emb
// staged in LDS; one __syncthreads vmcnt-drain makes the global writes
// visible to this single block), deleting the separate k_gtab launch.
// Main loop identical to the proven R16/R18 structure except the
// activation divisions are raw v_rcp.
// ---------------------------------------------------------------------------
__global__ __attribute__((amdgpu_flat_work_group_size(512, 512),
                          amdgpu_waves_per_eu(2, 2)))
void k_lstm(
        const float* __restrict__ emb, const float* __restrict__ Wih,
        const float* __restrict__ bih, const float* __restrict__ bhh,
        const float* __restrict__ Whh, float* __restrict__ Gtab,
        const int* __restrict__ x,
        float* __restrict__ out, float* __restrict__ hT, float* __restrict__ cT) {
    int tid = threadIdx.x;
    int wv  = tid >> 6;    // wave 0..7: owns j-range [16wv, 16wv+16)
    int l   = tid & 63;
    int cn  = l & 15;      // MFMA A-row within tile
    int kg  = l >> 4;      // k-group 0..3
    int cb  = l & 3;       // batch for B-frag load (col c = batch c&3)
    int jr  = l >> 2;      // activation: row within tile (0..15)
    int bb  = l & 3;       // activation: batch
    int aj  = 16 * wv + jr; // activation: global row j

    bool r1 = (l >> 2) & 1;   // loop-invariant select bits: r = (l>>2)&3
    bool r2 = (l >> 2) & 2;

    __shared__ float elds[Vn][En];                   // emb staged (16 KB)
    __shared__ int xb[4][520];                       // PRE-SCALED byte offsets
    __shared__ alignas(16) _Float16 hbuf[2][4][144]; // h fp16, double-buffered

    for (int i = tid; i < Vn * En; i += 512) ((float*)elds)[i] = emb[i];
    for (int i = tid; i < Bn * Sn; i += 512) xb[i >> 9][i & 511] = x[i] * 2048;
    if (tid < 4) xb[tid][512] = 0;                   // sentinel for s=511 prefetch
    for (int i = tid; i < 2 * 4 * 144; i += 512) ((_Float16*)hbuf)[i] = (_Float16)0.0f;
    __syncthreads();

    // ---- Gtab prologue: thread tid owns gate-row jg = tid ----
    {
        int jg = tid;                       // g*128 + j
        const float4* wr = (const float4*)(Wih + jg * En);
        float4 w[8];
#pragma unroll
        for (int i = 0; i < 8; i++) w[i] = wr[i];
        float bias = bih[jg] + bhh[jg];
        int dst = (jg & 127) * 4 + (jg >> 7);
        for (int v = 0; v < Vn; v++) {
            const float4* e4 = (const float4*)elds[v];
            float acc = bias;
#pragma unroll
            for (int i = 0; i < 8; i++) {
                float4 e = e4[i];
                acc += w[i].x * e.x + w[i].y * e.y + w[i].z * e.z + w[i].w * e.w;
            }
            Gtab[v * G4H + dst] = acc;
        }
    }

    // ---- A-fragments: af[gate][kc], loaded + converted ONCE ----
    half8 af[4][4];
#pragma unroll
    for (int g = 0; g < 4; g++) {
#pragma unroll
        for (int kc = 0; kc < 4; kc++) {
            int row = g * Hn + 16 * wv + cn;
            int kb  = kc * 32 + kg * 8;
            const float4* p = (const float4*)(Whh + row * Hn + kb);
            float4 lo = p[0], hi = p[1];
            half8 a = { (_Float16)lo.x, (_Float16)lo.y, (_Float16)lo.z, (_Float16)lo.w,
                        (_Float16)hi.x, (_Float16)hi.y, (_Float16)hi.z, (_Float16)hi.w };
            af[g][kc] = a;
        }
    }

    float c_ = 0.f, h_ = 0.f;
    const char* gbase = (const char*)Gtab + aj * 16;   // + xb byte offset
    float* outp = out + bb * Sn * Hn + aj;
    __syncthreads();   // drains Gtab stores (vmcnt 0) + barrier: reads safe

    float4 gx4 = *(const float4*)(gbase + xb[bb][0]);

#pragma unroll 2
    for (int s = 0; s < Sn; s++) {
        // B-fragments from hbuf[s&1]: col = batch, k = kc*32+kg*8+(0..7)
        half8 bf[4];
#pragma unroll
        for (int kc = 0; kc < 4; kc++)
            bf[kc] = *(const half8*)&hbuf[s & 1][cb][kc * 32 + kg * 8];

        // 16 MFMAs: 4 gates x 4 K-chunks, fp32 accumulate
        floatx4 d[4];
#pragma unroll
        for (int g = 0; g < 4; g++) {
            floatx4 acc = { 0.f, 0.f, 0.f, 0.f };
#pragma unroll
            for (int kc = 0; kc < 4; kc++)
                acc = __builtin_amdgcn_mfma_f32_16x16x32_f16(af[g][kc], bf[kc], acc, 0, 0, 0);
            d[g] = acc;
        }

        // prefetch NEXT step's gx (sentinel makes s=511 safe)
        float4 ngx = *(const float4*)(gbase + xb[bb][s + 1]);

        // direct select: lane's own reg r = (l>>2)&3 IS (row jr, batch bb)
        float ex[4];
#pragma unroll
        for (int g = 0; g < 4; g++) {
            float lo = r1 ? d[g][1] : d[g][0];
            float hi = r1 ? d[g][3] : d[g][2];
            ex[g] = r2 ? hi : lo;
        }

        float gi = gx4.x + ex[0];
        float gf = gx4.y + ex[1];
        float gg = gx4.z + ex[2];
        float go = gx4.w + ex[3];
        c_ = fsigmoid(gf) * c_ + fsigmoid(gi) * ftanh(gg);
        h_ = fsigmoid(go) * ftanh(c_);

        *outp = h_;  outp += Hn;                 // fire-and-forget
        hbuf[(s & 1) ^ 1][bb][aj] = (_Float16)h_;

        gx4 = ngx;
        // LDS-only barrier: hbuf visible to all waves; vmcnt NOT drained.
        asm volatile("s_waitcnt lgkmcnt(0)\n\ts_barrier" ::: "memory");
    }
    hT[bb * Hn + aj] = h_;
    cT[bb * Hn + aj] = c_;
}

// ---------------------------------------------------------------------------
// Kernel C: K-GEMV writing TRANSPOSED koT[b][u][i][4] (coalesced score reads).
// ---------------------------------------------------------------------------
__global__ __launch_bounds__(128) void k_k(
        const float* __restrict__ out, const float* __restrict__ Wk,
        const float* __restrict__ bk, float* __restrict__ koT) {
    int bs  = blockIdx.x;
    int b   = bs >> 9;
    int s   = bs & (Sn - 1);
    int tid = threadIdx.x;
    __shared__ float o[Hn];
    o[tid] = out[bs * Hn + tid];
    __syncthreads();
    const float4* wr = (const float4*)(Wk + tid * Hn);
    float acc = bk[tid];
#pragma unroll
    for (int i = 0; i < Hn / 4; i++) {
        float4 w4 = wr[i];
        acc += w4.x * o[4*i] + w4.y * o[4*i+1] + w4.z * o[4*i+2] + w4.w * o[4*i+3];
    }
    koT[b * 65536 + (tid >> 2) * 2048 + s * 4 + (tid & 3)] = acc;
}

// ---------------------------------------------------------------------------
// Kernel D: FUSED q-GEMV + scores + softmax + ctx + logits GEMV.
// Block per (b,t), 512 threads. ctx never leaves LDS. rcp-based tanh.
// ---------------------------------------------------------------------------
__global__ __launch_bounds__(512) void k_attn(
        const float* __restrict__ koT, const float* __restrict__ vvec,
        const float* __restrict__ out,
        const float* __restrict__ Wq, const float* __restrict__ bq,
        const float* __restrict__ Wf, const float* __restrict__ bf,
        float* __restrict__ logits) {
    int b   = blockIdx.x >> 9;
    int t   = blockIdx.x & (Sn - 1);
    int tid = threadIdx.x;
    int wv  = tid >> 6;
    __shared__ float qs[Hn];
    __shared__ float vs[Hn];
    __shared__ float oc[2 * Hn];   // [out_t | ctx_t]
    __shared__ float sc[Sn];
    __shared__ float wmax[8];
    __shared__ float wsum[8];
    __shared__ float part[16][Hn];

    if (tid < Hn) {
        oc[tid] = out[(b * Sn + t) * Hn + tid];
        vs[tid] = vvec[tid];
    }
    __syncthreads();

    // --- q_t = bq + Wq @ out_t: thread (h = tid&127, kq = tid>>7) ---
    {
        int h = tid & 127, kq = tid >> 7;
        const float4* wr = (const float4*)(Wq + h * Hn + kq * 32);
        const float* ob = oc + kq * 32;
        float a = 0.0f;
#pragma unroll
        for (int i = 0; i < 8; i++) {
            float4 w4 = wr[i];
            a += w4.x * ob[4*i] + w4.y * ob[4*i+1] + w4.z * ob[4*i+2] + w4.w * ob[4*i+3];
        }
        part[kq][h] = a;
    }
    __syncthreads();
    if (tid < Hn)
        qs[tid] = bq[tid] + part[0][tid] + part[1][tid] + part[2][tid] + part[3][tid];
    __syncthreads();

    // --- scores: thread tid = key index i; koT reads coalesced ---
    float a = -1e30f;
    if (tid <= t) {
        const float4* kT = (const float4*)koT + b * 16384 + tid;
        float s = 0.0f;
#pragma unroll
        for (int u = 0; u < Hn / 4; u++) {
            float4 k4 = kT[u * 512];
            s += vs[4*u]   * ftanh(qs[4*u]   + k4.x);
            s += vs[4*u+1] * ftanh(qs[4*u+1] + k4.y);
            s += vs[4*u+2] * ftanh(qs[4*u+2] + k4.z);
            s += vs[4*u+3] * ftanh(qs[4*u+3] + k4.w);
        }
        sc[tid] = s;
        a = s;
    }
#pragma unroll
    for (int off = 32; off > 0; off >>= 1) a = fmaxf(a, __shfl_xor(a, off));
    if ((tid & 63) == 0) wmax[wv] = a;
    __syncthreads();
    float m = wmax[0];
#pragma unroll
    for (int r = 1; r < 8; r++) m = fmaxf(m, wmax[r]);

    float ev = 0.0f;
    if (tid <= t) {
        ev = __expf(sc[tid] - m);
        sc[tid] = ev;
    }
    float ssum = ev;
#pragma unroll
    for (int off = 32; off > 0; off >>= 1) ssum += __shfl_xor(ssum, off);
    if ((tid & 63) == 0) wsum[wv] = ssum;
    __syncthreads();
    float tot = wsum[0];
#pragma unroll
    for (int r = 1; r < 8; r++) tot += wsum[r];
    float inv = frcp(tot);   // tot >= 1 (m is the max): rcp safe

    // --- ctx: i-slice = tid>>5 (16 slices), float4 column = tid&31 ---
    int hq = tid & 31;
    int is = tid >> 5;
    float4 acc = {0.0f, 0.0f, 0.0f, 0.0f};
    const float4* ob4 = (const float4*)(out + b * Sn * Hn);
    for (int i = is; i <= t; i += 16) {
        float s = sc[i];
        float4 o4 = ob4[i * (Hn / 4) + hq];
        acc.x += s * o4.x; acc.y += s * o4.y;
        acc.z += s * o4.z; acc.w += s * o4.w;
    }
    ((float4*)part[is])[hq] = acc;
    __syncthreads();
    if (tid < Hn) {
        float sum2 = 0.0f;
#pragma unroll
        for (int r = 0; r < 16; r++) sum2 += part[r][tid];
        oc[Hn + tid] = sum2 * inv;     // ctx stays in LDS
    }
    __syncthreads();

    // --- logits = bf + Wf @ [out_t | ctx_t]: thread (v = tid&127, kq) ---
    {
        int v = tid & 127, kq = tid >> 7;
        const float4* wr = (const float4*)(Wf + v * 2 * Hn + kq * 64);
        const float* ob = oc + kq * 64;
        float a2 = 0.0f;
#pragma unroll
        for (int i = 0; i < 16; i++) {
            float4 w4 = wr[i];
            a2 += w4.x * ob[4*i] + w4.y * ob[4*i+1] + w4.z * ob[4*i+2] + w4.w * ob[4*i+3];
        }
        part[kq][v] = a2;
    }
    __syncthreads();
    if (tid < Hn)
        logits[(b * Sn + t) * Vn + tid] =
            bf[tid] + part[0][tid] + part[1][tid] + part[2][tid] + part[3][tid];
}

extern "C" void kernel_launch(void* const* d_in, const int* in_sizes, int n_in,
                              void* d_out, int out_size, void* d_ws, size_t ws_size,
                              hipStream_t stream) {
    const int*   x   = (const int*)d_in[0];
    const float* emb = (const float*)d_in[1];
    const float* Wih = (const float*)d_in[2];
    const float* Whh = (const float*)d_in[3];
    const float* bih = (const float*)d_in[4];
    const float* bhh = (const float*)d_in[5];
    const float* Wq  = (const float*)d_in[6];
    const float* bq  = (const float*)d_in[7];
    const float* Wk  = (const float*)d_in[8];
    const float* bk  = (const float*)d_in[9];
    const float* v   = (const float*)d_in[10];
    const float* Wf  = (const float*)d_in[11];
    const float* bf  = (const float*)d_in[12];

    float* logits = (float*)d_out;                 // (B,S,V) = 262144
    float* hT     = logits + Bn * Sn * Vn;         // (B,H)   = 512
    float* cT     = hT + Bn * Hn;                  // (B,H)   = 512

    float* ws   = (float*)d_ws;
    float* Gtab = ws;                               // V*4H   = 65536 floats
    float* outb = ws + 65536;                       // B*S*H  = 262144
    float* koT  = ws + 65536 + 262144;              // B*S*H  = 262144 (transposed)

    k_lstm<<<1, 512, 0, stream>>>(emb, Wih, bih, bhh, Whh, Gtab, x, outb, hT, cT);
    k_k<<<Bn * Sn, 128, 0, stream>>>(outb, Wk, bk, koT);
    k_attn<<<Bn * Sn, 512, 0, stream>>>(koT, v, outb, Wq, bq, Wf, bf, logits);
}